// Round 5
// baseline (319.129 us; speedup 1.0000x reference)
//
#include <hip/hip_runtime.h>
#include <hip/hip_bf16.h>

#define B_  512
#define L_  100
#define LP_ 112      // rows padded to 7*16 (Hws row count)
#define LQ_ 128      // HT row length (j padded to 128 for clean K-slices)
#define D_  128
#define SH_ 136      // LDS ushort stride, kernel 1
#define SP_ 136      // Pt ushort stride, kernel 2

#define HWS_BYTES  (512ULL * LP_ * D_ * 2ULL)          // 14,680,064
#define HT_OFFSET  HWS_BYTES                            // 16B aligned

typedef unsigned short ushort_t;
typedef __attribute__((ext_vector_type(8))) unsigned short us8;
typedef __attribute__((ext_vector_type(8))) __bf16 bf8;
typedef __attribute__((ext_vector_type(4))) float f4;
typedef __attribute__((ext_vector_type(4))) float f4v;
typedef __attribute__((ext_vector_type(4))) unsigned int ui4;

__device__ __forceinline__ float b2f(ushort_t u) {
  union { unsigned i; float f; } v; v.i = ((unsigned)u) << 16; return v.f;
}
__device__ __forceinline__ ushort_t f2b(float f) {
  unsigned u = __float_as_uint(f);
  u += 0x7fffu + ((u >> 16) & 1u);   // RNE
  return (ushort_t)(u >> 16);
}
__device__ __forceinline__ us8 pack8(const float* x) {
  union { __hip_bfloat162 h; unsigned u; } cv;
  ui4 pk;
#pragma unroll
  for (int t = 0; t < 4; ++t) {
    cv.h = __float22bfloat162_rn(make_float2(x[2 * t], x[2 * t + 1]));
    pk[t] = cv.u;
  }
  return __builtin_bit_cast(us8, pk);
}

// ---------------- kernel 1: gather + transpose into workspace ----------------
// grid 512, block 256. Hws[b][r<112][d<128] bf16 (rows>=100 zero),
// HTws[b][d<128][j<128] bf16 (j>=100 zero).
__global__ __launch_bounds__(256, 4)
void prep_kernel(const int* __restrict__ inp, const float* __restrict__ embF,
                 ushort_t* __restrict__ Hws, ushort_t* __restrict__ HTws) {
  __shared__ __align__(16) ushort_t Hs[LQ_ * SH_];   // 34.8 KB, rows 100..127 zero
  const int b = blockIdx.x, tid = threadIdx.x;

  for (int u = tid; u < LQ_ * 16; u += 256) {        // 8 iters: (row, 8-float chunk)
    int r = u >> 4, ch = u & 15;
    us8 o = {0, 0, 0, 0, 0, 0, 0, 0};
    if (r < L_) {
      int idx = inp[b * L_ + r];
      const float* src = embF + ((size_t)idx << 7) + ch * 8;
      f4v v0 = *(const f4v*)src;
      f4v v1 = *(const f4v*)(src + 4);
      float x[8];
#pragma unroll
      for (int t = 0; t < 4; ++t) { x[t] = v0[t]; x[4 + t] = v1[t]; }
      o = pack8(x);
    }
    *(us8*)&Hs[r * SH_ + ch * 8] = o;
    if (r < LP_) *(us8*)(Hws + (size_t)b * LP_ * D_ + r * D_ + ch * 8) = o;  // coalesced
  }
  __syncthreads();

  // HT: unit (d = u&127, jch = u>>7); LDS reads conflict-free (lanes span d -> all banks)
  for (int u = tid; u < D_ * 16; u += 256) {         // 8 iters
    int d = u & 127, jch = u >> 7;
    us8 vv;
#pragma unroll
    for (int t = 0; t < 8; ++t) vv[t] = Hs[(jch * 8 + t) * SH_ + d];
    *(us8*)(HTws + (size_t)b * D_ * LQ_ + d * LQ_ + jch * 8) = vv;
  }
}

// ---------------- kernel 2: attention, barrier-free ----------------
// grid (512, 7), block 256 (4 waves). Each wave computes the FULL 16x112 E tile
// (redundant MFMA is cheap), in-register softmax via quarter-wave shfl, P through
// wave-private LDS, PV from HTws. Zero __syncthreads.
__global__ __launch_bounds__(256, 3)
void attn_kernel(const int* __restrict__ adjG,
                 const float* __restrict__ a0F, const float* __restrict__ a1F,
                 const float* __restrict__ a2F, const float* __restrict__ a3F,
                 const ushort_t* __restrict__ Hws, const ushort_t* __restrict__ HTws,
                 float* __restrict__ outG) {
  __shared__ __align__(16) ushort_t Pt[4 * 16 * SP_];   // 17.4 KB, wave-private quarters
  const int b = blockIdx.x, mi = blockIdx.y, tid = threadIdx.x;
  const int w = tid >> 6, lane = tid & 63, c = lane & 15, q = lane >> 4;
  const ushort_t* Hb  = Hws  + (size_t)b * LP_ * D_;
  const ushort_t* HTb = HTws + (size_t)b * D_ * LQ_;

  // ---- A-side: h row (m = c), a_k folded in-register ----
  float hf[4][8];
#pragma unroll
  for (int ks = 0; ks < 4; ++ks) {
    us8 hr = *(const us8*)&Hb[(mi * 16 + c) * D_ + ks * 32 + q * 8];
#pragma unroll
    for (int jj = 0; jj < 8; ++jj) hf[ks][jj] = b2f(hr[jj]);
  }
  const float* aPk[4] = {a0F, a1F, a2F, a3F};
  us8 Af[4][4];
#pragma unroll
  for (int k = 0; k < 4; ++k)
#pragma unroll
    for (int ks = 0; ks < 4; ++ks) {
      const float* ap = aPk[k] + ks * 32 + q * 8;
      f4v av0 = *(const f4v*)ap;
      f4v av1 = *(const f4v*)(ap + 4);
      float p[8];
#pragma unroll
      for (int t = 0; t < 4; ++t) { p[t] = hf[ks][t] * av0[t]; p[4 + t] = hf[ks][4 + t] * av1[t]; }
      Af[k][ks] = pack8(p);
    }

  // ---- E over all 7 j-tiles; select+leaky to registers lg[nt][r] ----
  float lg[7][4];
#pragma unroll
  for (int nt = 0; nt < 7; ++nt) {
    us8 Bf[4];
#pragma unroll
    for (int ks = 0; ks < 4; ++ks)
      Bf[ks] = *(const us8*)&Hb[(nt * 16 + c) * D_ + ks * 32 + q * 8];
    f4 e0 = {0,0,0,0}, e1 = {0,0,0,0}, e2 = {0,0,0,0}, e3 = {0,0,0,0};
#pragma unroll
    for (int ks = 0; ks < 4; ++ks) {
      bf8 bb = __builtin_bit_cast(bf8, Bf[ks]);
      e0 = __builtin_amdgcn_mfma_f32_16x16x32_bf16(__builtin_bit_cast(bf8, Af[0][ks]), bb, e0, 0, 0, 0);
      e1 = __builtin_amdgcn_mfma_f32_16x16x32_bf16(__builtin_bit_cast(bf8, Af[1][ks]), bb, e1, 0, 0, 0);
      e2 = __builtin_amdgcn_mfma_f32_16x16x32_bf16(__builtin_bit_cast(bf8, Af[2][ks]), bb, e2, 0, 0, 0);
      e3 = __builtin_amdgcn_mfma_f32_16x16x32_bf16(__builtin_bit_cast(bf8, Af[3][ks]), bb, e3, 0, 0, 0);
    }
    // C/D: col=c (j in tile), row=q*4+r (i in tile)
    int j = nt * 16 + c;
#pragma unroll
    for (int r = 0; r < 4; ++r) {
      int i = mi * 16 + q * 4 + r;
      int t = 0;
      if (j < L_ && i < L_) t = adjG[((size_t)b * L_ + i) * L_ + j];   // coalesced over c
      float e = (t == 1) ? e0[r] : (t == 2) ? e1[r] : (t == 3) ? e2[r] : e3[r];
      e = (e > 0.f) ? e : 0.2f * e;               // leaky_relu(0.2)
      lg[nt][r] = (t >= 1) ? e : -9e15f;
    }
  }

  // ---- in-register softmax (reduce over c within same-q group + over nt) ----
  ushort_t* Pw = Pt + w * 16 * SP_;
#pragma unroll
  for (int r = 0; r < 4; ++r) {
    float m = lg[0][r];
#pragma unroll
    for (int nt = 1; nt < 7; ++nt) m = fmaxf(m, lg[nt][r]);
#pragma unroll
    for (int off = 1; off <= 8; off <<= 1) m = fmaxf(m, __shfl_xor(m, off, 64));
    float ex[7], s = 0.f;
#pragma unroll
    for (int nt = 0; nt < 7; ++nt) { ex[nt] = __expf(lg[nt][r] - m); s += ex[nt]; }
#pragma unroll
    for (int off = 1; off <= 8; off <<= 1) s += __shfl_xor(s, off, 64);
    float inv = 1.0f / s;
    int row = q * 4 + r;
#pragma unroll
    for (int nt = 0; nt < 7; ++nt) Pw[row * SP_ + nt * 16 + c] = f2b(ex[nt] * inv);
  }
  // zero-pad P cols 112..127 (each lane one (row, 4-col) strip)
#pragma unroll
  for (int t = 0; t < 4; ++t) Pw[(lane & 15) * SP_ + 112 + q * 4 + t] = 0;

  // ---- PV: out = P x H, B-side from HT (dense 16B loads); wave -> d-tiles {2w, 2w+1} ----
  us8 Pf[4];
#pragma unroll
  for (int ks = 0; ks < 4; ++ks)
    Pf[ks] = *(const us8*)&Pw[c * SP_ + ks * 32 + q * 8];
#pragma unroll
  for (int s2 = 0; s2 < 2; ++s2) {
    int nt2 = w * 2 + s2;
    us8 OB[4];
#pragma unroll
    for (int ks = 0; ks < 4; ++ks)
      OB[ks] = *(const us8*)&HTb[(nt2 * 16 + c) * LQ_ + ks * 32 + q * 8];
    f4 oc = {0,0,0,0};
#pragma unroll
    for (int ks = 0; ks < 4; ++ks)
      oc = __builtin_amdgcn_mfma_f32_16x16x32_bf16(__builtin_bit_cast(bf8, Pf[ks]),
                                                   __builtin_bit_cast(bf8, OB[ks]), oc, 0, 0, 0);
#pragma unroll
    for (int r = 0; r < 4; ++r) {
      int i = mi * 16 + q * 4 + r;
      if (i < L_) outG[((size_t)b * L_ + i) * (size_t)D_ + nt2 * 16 + c] = oc[r];
    }
  }
}

extern "C" void kernel_launch(void* const* d_in, const int* in_sizes, int n_in,
                              void* d_out, int out_size, void* d_ws, size_t ws_size,
                              hipStream_t stream) {
  (void)out_size; (void)ws_size;   // needs ws_size >= 31,457,280 B
  const int* inp = nullptr; const int* adj = nullptr;
  const float* emb = nullptr; const float* aP[4] = {nullptr, nullptr, nullptr, nullptr};
  int na = 0;
  for (int i = 0; i < n_in; ++i) {
    int s = in_sizes[i];
    if (s == 25600000)            emb = (const float*)d_in[i];
    else if (s == 5120000)        adj = (const int*)d_in[i];
    else if (s == 128 && na < 4)  aP[na++] = (const float*)d_in[i];
    else if (s == 51200 && !inp)  inp = (const int*)d_in[i];   // first 51200 = inputs
  }
  ushort_t* Hws  = (ushort_t*)d_ws;
  ushort_t* HTws = (ushort_t*)((char*)d_ws + HT_OFFSET);
  prep_kernel<<<dim3(B_), dim3(256), 0, stream>>>(inp, emb, Hws, HTws);
  attn_kernel<<<dim3(B_, 7), dim3(256), 0, stream>>>(
      adj, aP[0], aP[1], aP[2], aP[3], Hws, HTws, (float*)d_out);
}

// Round 6
// 216.385 us; speedup vs baseline: 1.4748x; 1.4748x over previous
//
#include <hip/hip_runtime.h>
#include <hip/hip_bf16.h>

#define B_  512
#define L_  100
#define D_  128
#define SP_ 136      // Pt ushort stride

typedef unsigned short ushort_t;
typedef __attribute__((ext_vector_type(8))) unsigned short us8;
typedef __attribute__((ext_vector_type(8))) __bf16 bf8;
typedef __attribute__((ext_vector_type(4))) float f4;
typedef __attribute__((ext_vector_type(4))) float f4v;
typedef __attribute__((ext_vector_type(4))) int i4v;
typedef __attribute__((ext_vector_type(4))) unsigned int ui4;

__device__ __forceinline__ float b2f(ushort_t u) {
  union { unsigned i; float f; } v; v.i = ((unsigned)u) << 16; return v.f;
}
__device__ __forceinline__ ushort_t f2b(float f) {
  unsigned u = __float_as_uint(f);
  u += 0x7fffu + ((u >> 16) & 1u);   // RNE
  return (ushort_t)(u >> 16);
}
__device__ __forceinline__ us8 pack8(const float* x) {
  union { __hip_bfloat162 h; unsigned u; } cv;
  ui4 pk;
#pragma unroll
  for (int t = 0; t < 4; ++t) {
    cv.h = __float22bfloat162_rn(make_float2(x[2 * t], x[2 * t + 1]));
    pk[t] = cv.u;
  }
  return __builtin_bit_cast(us8, pk);
}
// XOR-swizzled Hs index: element (row, col), rows/cols in [0,128).
// 16B chunks stay contiguous (b128-safe); chunk ^= row&15 spreads banks for
// both row-major b128 reads and column-walk scalar reads (transpose).
__device__ __forceinline__ int sw(int row, int col) {
  return row * 128 + ((((col >> 3) ^ row) & 15) << 3) + (col & 7);
}

// One block per batch, 448 threads = 7 waves; wave w owns M-tile w (rows w*16..w*16+15).
// Phases: [gather H + adj + a_k] B [E + select + in-register softmax -> Pt] B
//         [in-place swizzled transpose Hs -> H^T] B [PV, store f32 out].
__global__ __launch_bounds__(448, 4)
void CombineGraph_fused(const int* __restrict__ inp, const int* __restrict__ adjG,
                        const float* __restrict__ embF,
                        const float* __restrict__ a0F, const float* __restrict__ a1F,
                        const float* __restrict__ a2F, const float* __restrict__ a3F,
                        float* __restrict__ outG) {
  __shared__ __align__(16) ushort_t Hs[128 * 128];       // 32768 B, swizzled; becomes H^T
  __shared__ __align__(16) ushort_t Pt[7 * 16 * SP_];    // 30464 B, wave-private P tiles
  __shared__ __align__(4)  unsigned char adjS[10000];    // 10000 B, flat i*100+j
  __shared__ float aVf[4 * 128];                         //  2048 B
  // total 75280 B -> 2 blocks/CU

  const int b = blockIdx.x, tid = threadIdx.x;
  const int w = tid / 64, lane = tid & 63, c = lane & 15, q = lane >> 4;

  // ---- phase 0: stage a_k, gather H (f32 emb -> bf16, rows>=100 zero), adj ----
  for (int u = tid; u < 512; u += 448) {
    int k = u >> 7, d = u & 127;
    const float* ak = (k == 0) ? a0F : (k == 1) ? a1F : (k == 2) ? a2F : a3F;
    aVf[u] = ak[d];
  }
  for (int u = tid; u < 128 * 16; u += 448) {            // (row, 8-elem chunk)
    int r = u >> 4, ch = u & 15;
    us8 o = {0, 0, 0, 0, 0, 0, 0, 0};
    if (r < L_) {
      int idx = inp[b * L_ + r];
      const float* src = embF + ((size_t)idx << 7) + ch * 8;
      f4v v0 = *(const f4v*)src;
      f4v v1 = *(const f4v*)(src + 4);
      float x[8];
#pragma unroll
      for (int t = 0; t < 4; ++t) { x[t] = v0[t]; x[4 + t] = v1[t]; }
      o = pack8(x);
    }
    *(us8*)&Hs[sw(r, ch * 8)] = o;
  }
  for (int u = tid; u < 2500; u += 448) {                // adj: int4 -> packed uchar4
    i4v v = *(const i4v*)(adjG + (size_t)b * 10000 + u * 4);
    unsigned pk = (unsigned)(v[0] & 255) | ((unsigned)(v[1] & 255) << 8) |
                  ((unsigned)(v[2] & 255) << 16) | ((unsigned)(v[3] & 255) << 24);
    *(unsigned*)&adjS[u * 4] = pk;
  }
  __syncthreads();

  // ---- A-side: h row (m = c of tile w), a_k folded in-register ----
  const int mi = w;
  float hf[4][8];
#pragma unroll
  for (int ks = 0; ks < 4; ++ks) {
    us8 hr = *(const us8*)&Hs[sw(mi * 16 + c, ks * 32 + q * 8)];
#pragma unroll
    for (int jj = 0; jj < 8; ++jj) hf[ks][jj] = b2f(hr[jj]);
  }
  us8 Af[4][4];
#pragma unroll
  for (int k = 0; k < 4; ++k)
#pragma unroll
    for (int ks = 0; ks < 4; ++ks) {
      const float* ap = &aVf[k * 128 + ks * 32 + q * 8];  // broadcast within q-group
      f4v av0 = *(const f4v*)ap;
      f4v av1 = *(const f4v*)(ap + 4);
      float p[8];
#pragma unroll
      for (int t = 0; t < 4; ++t) { p[t] = hf[ks][t] * av0[t]; p[4 + t] = hf[ks][4 + t] * av1[t]; }
      Af[k][ks] = pack8(p);
    }

  // ---- E over all 7 j-tiles (this wave's 16 rows); select+leaky -> lg ----
  float lg[7][4];
#pragma unroll
  for (int nt = 0; nt < 7; ++nt) {
    f4 e0 = {0,0,0,0}, e1 = {0,0,0,0}, e2 = {0,0,0,0}, e3 = {0,0,0,0};
#pragma unroll
    for (int ks = 0; ks < 4; ++ks) {
      bf8 bb = __builtin_bit_cast(bf8, *(const us8*)&Hs[sw(nt * 16 + c, ks * 32 + q * 8)]);
      e0 = __builtin_amdgcn_mfma_f32_16x16x32_bf16(__builtin_bit_cast(bf8, Af[0][ks]), bb, e0, 0, 0, 0);
      e1 = __builtin_amdgcn_mfma_f32_16x16x32_bf16(__builtin_bit_cast(bf8, Af[1][ks]), bb, e1, 0, 0, 0);
      e2 = __builtin_amdgcn_mfma_f32_16x16x32_bf16(__builtin_bit_cast(bf8, Af[2][ks]), bb, e2, 0, 0, 0);
      e3 = __builtin_amdgcn_mfma_f32_16x16x32_bf16(__builtin_bit_cast(bf8, Af[3][ks]), bb, e3, 0, 0, 0);
    }
    int j = nt * 16 + c;
#pragma unroll
    for (int r = 0; r < 4; ++r) {
      int i = mi * 16 + q * 4 + r;
      int t = adjS[(i < L_ ? i : L_ - 1) * 100 + (j < L_ ? j : L_ - 1)];
      t = (i < L_ && j < L_) ? t : 0;
      float e = (t == 1) ? e0[r] : (t == 2) ? e1[r] : (t == 3) ? e2[r] : e3[r];
      e = (e > 0.f) ? e : 0.2f * e;               // leaky_relu(0.2)
      lg[nt][r] = (t >= 1) ? e : -9e15f;
    }
  }

  // ---- in-register softmax (reduce over 16 c-lanes within q-group, + over nt) ----
  ushort_t* Pw = Pt + w * 16 * SP_;
#pragma unroll
  for (int r = 0; r < 4; ++r) {
    float m = lg[0][r];
#pragma unroll
    for (int nt = 1; nt < 7; ++nt) m = fmaxf(m, lg[nt][r]);
#pragma unroll
    for (int off = 1; off <= 8; off <<= 1) m = fmaxf(m, __shfl_xor(m, off, 64));
    float ex[7], s = 0.f;
#pragma unroll
    for (int nt = 0; nt < 7; ++nt) { ex[nt] = __expf(lg[nt][r] - m); s += ex[nt]; }
#pragma unroll
    for (int off = 1; off <= 8; off <<= 1) s += __shfl_xor(s, off, 64);
    float inv = 1.0f / s;
    int row = q * 4 + r;
#pragma unroll
    for (int nt = 0; nt < 7; ++nt) Pw[row * SP_ + nt * 16 + c] = f2b(ex[nt] * inv);
  }
#pragma unroll
  for (int t = 0; t < 4; ++t) Pw[c * SP_ + 112 + q * 4 + t] = 0;   // zero K-pad 112..127

  __syncthreads();   // all E reads of Hs done

  // ---- in-place transpose of Hs (disjoint pair swaps; no barriers inside) ----
  for (int u = tid; u < 8192; u += 448) {
    int d0 = u >> 7, j0 = u & 127;
    bool up = (j0 > d0);
    int d = up ? d0 : 127 - d0;
    int j = up ? j0 : 127 - j0;          // (d<j) strictly, except harmless self-swap at j0==d0
    int ia = sw(d, j), ib = sw(j, d);
    ushort_t va = Hs[ia], vb = Hs[ib];
    Hs[ia] = vb; Hs[ib] = va;
  }
  __syncthreads();   // Hs now holds H^T: Hs_sw(d, j) = H[j][d]

  // ---- PV: out(16 x 128) = P(16 x 128) x H(128 x 128-pad); all 8 n-tiles per wave ----
  us8 Pf[4];
#pragma unroll
  for (int ks = 0; ks < 4; ++ks)
    Pf[ks] = *(const us8*)&Pw[c * SP_ + ks * 32 + q * 8];
#pragma unroll
  for (int nt2 = 0; nt2 < 8; ++nt2) {
    f4 oc = {0,0,0,0};
#pragma unroll
    for (int ks = 0; ks < 4; ++ks) {
      bf8 ob = __builtin_bit_cast(bf8, *(const us8*)&Hs[sw(nt2 * 16 + c, ks * 32 + q * 8)]);
      oc = __builtin_amdgcn_mfma_f32_16x16x32_bf16(__builtin_bit_cast(bf8, Pf[ks]), ob, oc, 0, 0, 0);
    }
#pragma unroll
    for (int r = 0; r < 4; ++r) {
      int i = mi * 16 + q * 4 + r;
      if (i < L_) outG[((size_t)b * L_ + i) * (size_t)D_ + nt2 * 16 + c] = oc[r];
    }
  }
}

extern "C" void kernel_launch(void* const* d_in, const int* in_sizes, int n_in,
                              void* d_out, int out_size, void* d_ws, size_t ws_size,
                              hipStream_t stream) {
  (void)d_ws; (void)ws_size; (void)out_size;
  const int* inp = nullptr; const int* adj = nullptr;
  const float* emb = nullptr; const float* aP[4] = {nullptr, nullptr, nullptr, nullptr};
  int na = 0;
  for (int i = 0; i < n_in; ++i) {
    int s = in_sizes[i];
    if (s == 25600000)            emb = (const float*)d_in[i];
    else if (s == 5120000)        adj = (const int*)d_in[i];
    else if (s == 128 && na < 4)  aP[na++] = (const float*)d_in[i];
    else if (s == 51200 && !inp)  inp = (const int*)d_in[i];   // first 51200 = inputs
  }
  CombineGraph_fused<<<dim3(B_), dim3(448), 0, stream>>>(
      inp, adj, emb, aP[0], aP[1], aP[2], aP[3], (float*)d_out);
}

// Round 7
// 209.874 us; speedup vs baseline: 1.5206x; 1.0310x over previous
//
#include <hip/hip_runtime.h>
#include <hip/hip_bf16.h>

#define B_  512
#define L_  100
#define D_  128
#define SP_ 136      // Pt ushort stride
#define SO_ 132      // Ot float stride (528 B rows: 16B-aligned, 2-way max bank alias)

typedef unsigned short ushort_t;
typedef __attribute__((ext_vector_type(8))) unsigned short us8;
typedef __attribute__((ext_vector_type(8))) __bf16 bf8;
typedef __attribute__((ext_vector_type(4))) float f4;
typedef __attribute__((ext_vector_type(4))) float f4v;
typedef __attribute__((ext_vector_type(4))) int i4v;
typedef __attribute__((ext_vector_type(4))) unsigned int ui4;

__device__ __forceinline__ float b2f(ushort_t u) {
  union { unsigned i; float f; } v; v.i = ((unsigned)u) << 16; return v.f;
}
__device__ __forceinline__ ushort_t f2b(float f) {
  unsigned u = __float_as_uint(f);
  u += 0x7fffu + ((u >> 16) & 1u);   // RNE
  return (ushort_t)(u >> 16);
}
__device__ __forceinline__ us8 pack8(const float* x) {
  union { __hip_bfloat162 h; unsigned u; } cv;
  ui4 pk;
#pragma unroll
  for (int t = 0; t < 4; ++t) {
    cv.h = __float22bfloat162_rn(make_float2(x[2 * t], x[2 * t + 1]));
    pk[t] = cv.u;
  }
  return __builtin_bit_cast(us8, pk);
}
// XOR-swizzled Hs index (16B chunks contiguous; chunk ^= row&15)
__device__ __forceinline__ int sw(int row, int col) {
  return row * 128 + ((((col >> 3) ^ row) & 15) << 3) + (col & 7);
}

// One block per batch, 448 threads = 7 waves; wave w owns M-tile w.
// smem pool carve (bytes):
//   [0,     32768)  Hs   128x128 bf16 swizzled (later: H^T; later: aliased by Ot)
//   [32768, 63232)  Pt   7 x 16 x SP_ bf16     (later: aliased by Ot)
//   [63232, 73232)  adjS 100x100 u8
//   [73232, 75280)  aVf  4x128 f32
// Ot (f32, stride SO_) aliases [0, 59136) after the PV-read barrier.
__global__ __launch_bounds__(448, 4)
void CombineGraph_fused(const int* __restrict__ inp, const int* __restrict__ adjG,
                        const float* __restrict__ embF,
                        const float* __restrict__ a0F, const float* __restrict__ a1F,
                        const float* __restrict__ a2F, const float* __restrict__ a3F,
                        float* __restrict__ outG) {
  __shared__ __align__(16) unsigned char smem[75280];
  ushort_t* Hs = (ushort_t*)smem;
  ushort_t* Pt = (ushort_t*)(smem + 32768);
  unsigned char* adjS = smem + 63232;
  float* aVf = (float*)(smem + 73232);

  const int b = blockIdx.x, tid = threadIdx.x;
  const int w = tid / 64, lane = tid & 63, c = lane & 15, q = lane >> 4;

  // ---- phase 0: stage a_k, gather H (f32 emb -> bf16, rows>=100 zero), adj ----
  for (int u = tid; u < 512; u += 448) {
    int k = u >> 7, d = u & 127;
    const float* ak = (k == 0) ? a0F : (k == 1) ? a1F : (k == 2) ? a2F : a3F;
    aVf[u] = ak[d];
  }
  for (int u = tid; u < 128 * 16; u += 448) {            // (row, 8-elem chunk)
    int r = u >> 4, ch = u & 15;
    us8 o = {0, 0, 0, 0, 0, 0, 0, 0};
    if (r < L_) {
      int idx = inp[b * L_ + r];
      const float* src = embF + ((size_t)idx << 7) + ch * 8;
      f4v v0 = *(const f4v*)src;
      f4v v1 = *(const f4v*)(src + 4);
      float x[8];
#pragma unroll
      for (int t = 0; t < 4; ++t) { x[t] = v0[t]; x[4 + t] = v1[t]; }
      o = pack8(x);
    }
    *(us8*)&Hs[sw(r, ch * 8)] = o;
  }
  for (int u = tid; u < 2500; u += 448) {                // adj: int4 -> packed uchar4
    i4v v = *(const i4v*)(adjG + (size_t)b * 10000 + u * 4);
    unsigned pk = (unsigned)(v[0] & 255) | ((unsigned)(v[1] & 255) << 8) |
                  ((unsigned)(v[2] & 255) << 16) | ((unsigned)(v[3] & 255) << 24);
    *(unsigned*)&adjS[u * 4] = pk;
  }
  __syncthreads();

  // ---- A-side: h row (m = c of tile w), a_k folded in-register ----
  const int mi = w;
  float hf[4][8];
#pragma unroll
  for (int ks = 0; ks < 4; ++ks) {
    us8 hr = *(const us8*)&Hs[sw(mi * 16 + c, ks * 32 + q * 8)];
#pragma unroll
    for (int jj = 0; jj < 8; ++jj) hf[ks][jj] = b2f(hr[jj]);
  }
  us8 Af[4][4];
#pragma unroll
  for (int k = 0; k < 4; ++k)
#pragma unroll
    for (int ks = 0; ks < 4; ++ks) {
      const float* ap = &aVf[k * 128 + ks * 32 + q * 8];
      f4v av0 = *(const f4v*)ap;
      f4v av1 = *(const f4v*)(ap + 4);
      float p[8];
#pragma unroll
      for (int t = 0; t < 4; ++t) { p[t] = hf[ks][t] * av0[t]; p[4 + t] = hf[ks][4 + t] * av1[t]; }
      Af[k][ks] = pack8(p);
    }

  // ---- E over all 7 j-tiles (this wave's 16 rows); select+leaky -> lg ----
  float lg[7][4];
#pragma unroll
  for (int nt = 0; nt < 7; ++nt) {
    f4 e0 = {0,0,0,0}, e1 = {0,0,0,0}, e2 = {0,0,0,0}, e3 = {0,0,0,0};
#pragma unroll
    for (int ks = 0; ks < 4; ++ks) {
      bf8 bb = __builtin_bit_cast(bf8, *(const us8*)&Hs[sw(nt * 16 + c, ks * 32 + q * 8)]);
      e0 = __builtin_amdgcn_mfma_f32_16x16x32_bf16(__builtin_bit_cast(bf8, Af[0][ks]), bb, e0, 0, 0, 0);
      e1 = __builtin_amdgcn_mfma_f32_16x16x32_bf16(__builtin_bit_cast(bf8, Af[1][ks]), bb, e1, 0, 0, 0);
      e2 = __builtin_amdgcn_mfma_f32_16x16x32_bf16(__builtin_bit_cast(bf8, Af[2][ks]), bb, e2, 0, 0, 0);
      e3 = __builtin_amdgcn_mfma_f32_16x16x32_bf16(__builtin_bit_cast(bf8, Af[3][ks]), bb, e3, 0, 0, 0);
    }
    int j = nt * 16 + c;
#pragma unroll
    for (int r = 0; r < 4; ++r) {
      int i = mi * 16 + q * 4 + r;
      int t = adjS[(i < L_ ? i : L_ - 1) * 100 + (j < L_ ? j : L_ - 1)];
      t = (i < L_ && j < L_) ? t : 0;
      float e = (t == 1) ? e0[r] : (t == 2) ? e1[r] : (t == 3) ? e2[r] : e3[r];
      e = (e > 0.f) ? e : 0.2f * e;               // leaky_relu(0.2)
      lg[nt][r] = (t >= 1) ? e : -9e15f;
    }
  }

  // ---- in-register softmax (reduce over 16 c-lanes within q-group, + over nt) ----
  ushort_t* Pw = Pt + w * 16 * SP_;
#pragma unroll
  for (int r = 0; r < 4; ++r) {
    float m = lg[0][r];
#pragma unroll
    for (int nt = 1; nt < 7; ++nt) m = fmaxf(m, lg[nt][r]);
#pragma unroll
    for (int off = 1; off <= 8; off <<= 1) m = fmaxf(m, __shfl_xor(m, off, 64));
    float ex[7], s = 0.f;
#pragma unroll
    for (int nt = 0; nt < 7; ++nt) { ex[nt] = __expf(lg[nt][r] - m); s += ex[nt]; }
#pragma unroll
    for (int off = 1; off <= 8; off <<= 1) s += __shfl_xor(s, off, 64);
    float inv = 1.0f / s;
    int row = q * 4 + r;
#pragma unroll
    for (int nt = 0; nt < 7; ++nt) Pw[row * SP_ + nt * 16 + c] = f2b(ex[nt] * inv);
  }
#pragma unroll
  for (int t = 0; t < 4; ++t) Pw[c * SP_ + 112 + q * 4 + t] = 0;   // zero K-pad 112..127

  __syncthreads();   // all E reads of Hs done

  // ---- in-place transpose of Hs (disjoint pair swaps) ----
  for (int u = tid; u < 8192; u += 448) {
    int d0 = u >> 7, j0 = u & 127;
    bool up = (j0 > d0);
    int d = up ? d0 : 127 - d0;
    int j = up ? j0 : 127 - j0;
    int ia = sw(d, j), ib = sw(j, d);
    ushort_t va = Hs[ia], vb = Hs[ib];
    Hs[ia] = vb; Hs[ib] = va;
  }
  __syncthreads();   // Hs now holds H^T

  // ---- PV: accumulate all 8 n-tiles into registers ----
  us8 Pf[4];
#pragma unroll
  for (int ks = 0; ks < 4; ++ks)
    Pf[ks] = *(const us8*)&Pw[c * SP_ + ks * 32 + q * 8];
  f4 oc[8];
#pragma unroll
  for (int nt2 = 0; nt2 < 8; ++nt2) {
    f4 a = {0,0,0,0};
#pragma unroll
    for (int ks = 0; ks < 4; ++ks) {
      bf8 ob = __builtin_bit_cast(bf8, *(const us8*)&Hs[sw(nt2 * 16 + c, ks * 32 + q * 8)]);
      a = __builtin_amdgcn_mfma_f32_16x16x32_bf16(__builtin_bit_cast(bf8, Pf[ks]), ob, a, 0, 0, 0);
    }
    oc[nt2] = a;
  }
  __syncthreads();   // all Hs/Pt reads complete block-wide; safe to alias

  // ---- stage to LDS row-major, then fully-coalesced dwordx4 stores ----
  float* Ot = (float*)smem;                    // wave w region: [w*16*SO_, ...)
#pragma unroll
  for (int nt2 = 0; nt2 < 8; ++nt2)
#pragma unroll
    for (int r = 0; r < 4; ++r)
      Ot[(w * 16 + q * 4 + r) * SO_ + nt2 * 16 + c] = oc[nt2][r];
  // same-wave LDS RAW: compiler inserts lgkmcnt; no barrier needed.
#pragma unroll
  for (int it = 0; it < 8; ++it) {
    int u = it * 64 + lane;                    // wave-local: 16 rows x 32 f4-chunks
    int row16 = u >> 5, col4 = u & 31;
    int i = w * 16 + row16;
    if (i < L_) {
      f4 vv = *(const f4*)&Ot[(w * 16 + row16) * SO_ + col4 * 4];
      *(f4*)&outG[((size_t)b * L_ + i) * D_ + col4 * 4] = vv;
    }
  }
}

extern "C" void kernel_launch(void* const* d_in, const int* in_sizes, int n_in,
                              void* d_out, int out_size, void* d_ws, size_t ws_size,
                              hipStream_t stream) {
  (void)d_ws; (void)ws_size; (void)out_size;
  const int* inp = nullptr; const int* adj = nullptr;
  const float* emb = nullptr; const float* aP[4] = {nullptr, nullptr, nullptr, nullptr};
  int na = 0;
  for (int i = 0; i < n_in; ++i) {
    int s = in_sizes[i];
    if (s == 25600000)            emb = (const float*)d_in[i];
    else if (s == 5120000)        adj = (const int*)d_in[i];
    else if (s == 128 && na < 4)  aP[na++] = (const float*)d_in[i];
    else if (s == 51200 && !inp)  inp = (const int*)d_in[i];
  }
  CombineGraph_fused<<<dim3(B_), dim3(448), 0, stream>>>(
      inp, adj, emb, aP[0], aP[1], aP[2], aP[3], (float*)d_out);
}